// Round 11
// baseline (607.015 us; speedup 1.0000x reference)
//
#include <hip/hip_runtime.h>
#include <hip/hip_bf16.h>
#include <type_traits>

// ResGatedGraphConv x3 + softmax.
// R11: single persistent mega-kernel, 6 device-scope grid barriers (launch
// boundaries were ~7us each x 7 kernels). Flat fp16 [K|QV|S] rows (R8 layout,
// fastest gather) + kpre/exp2 sigmoid + zero-row padded ELL (uniform rounds)
// + ping-pong 2x8 edge-load pipeline. fp16 MFMA GEMMs, fp32 accumulate.
// N=20000 nodes, E=320000 edges, dims 256 -> 256 -> 128 -> 64.

#define NN 20000
#define EE 320000
#define ELLW 64   // max degree slot; Poisson(16) => P(deg>64) ~ 1e-19
#define NL2E -1.4426950408889634f  // -log2(e)

typedef _Float16 half8 __attribute__((ext_vector_type(8)));
typedef _Float16 half4 __attribute__((ext_vector_type(4)));
typedef _Float16 half2v __attribute__((ext_vector_type(2)));
typedef float f32x4 __attribute__((ext_vector_type(4)));

__device__ __forceinline__ _Float16 f2h(float f) { return (_Float16)f; }

struct MegaParams {
    const float* x;
    const int* ei;
    const float* w[3][4];  // [layer][grp k,q,v,skip]
    const float* b[3][4];  // [layer][grp] (skip slot = conv bias)
    _Float16* Xh;
    _Float16* KQVS;   // (NN+1) rows; row NN = zeros (padded-edge target)
    _Float16* H1h;
    _Float16* H2h;
    _Float16* wt[3];
    float* cb[3];
    int* i64flag;
    int* deg;
    unsigned short* ell;
    unsigned* bar;    // monotonic barrier counter (memset to 0 pre-launch)
    float* out;
};

// ---------------------------------------------------------------------------
// Grid barrier: monotonic counter, target = phase_idx * gridDim.x. All blocks
// are co-resident (grid sized by occupancy query), so spin is deadlock-free.
// __threadfence = agent-scope fence (release before arrive, acquire after).
__device__ __forceinline__ void gbar(unsigned* cnt, unsigned target) {
    __syncthreads();
    if (threadIdx.x == 0) {
        __threadfence();
        __hip_atomic_fetch_add(cnt, 1u, __ATOMIC_RELEASE,
                               __HIP_MEMORY_SCOPE_AGENT);
        while (__hip_atomic_load(cnt, __ATOMIC_ACQUIRE,
                                 __HIP_MEMORY_SCOPE_AGENT) < target)
            __builtin_amdgcn_s_sleep(2);
        __threadfence();
    }
    __syncthreads();
}

// ---------------------------------------------------------------------------
// fp16 MFMA GEMM tile: C = A[M,K] @ Bt[N,K]^T + catbias -> fp16 O[M][N].
// 128x128 tile, BK=32, double-buffered staging, one barrier per K-iter.
// Leading __syncthreads: called repeatedly per block (LDS WAR across calls).
__device__ void gemm_tile(int bm, int bn, const _Float16* __restrict__ A,
                          const _Float16* __restrict__ Bt,
                          const float* __restrict__ catbias,
                          _Float16* __restrict__ O, int M, int K, int N) {
    __shared__ _Float16 As[2][4096];  // [buf][row*32+k], 16 KB
    __shared__ _Float16 Bs[2][4096];
    __syncthreads();  // previous call's LDS reads done before re-staging

    const int tid = threadIdx.x;
    const int wid = tid >> 6;
    const int lane = tid & 63;
    const int tile_m = bm * 128;
    const int tile_n = bn * 128;
    const int wm = (wid & 1) * 64;
    const int wn = (wid >> 1) * 64;

    const int st_row = (wid << 4) + (lane >> 2);
    const int st_kc = (lane & 3) << 3;

    auto stage = [&](int buf, int kt) {
#pragma unroll
        for (int j = 0; j < 2; ++j) {
            int ar = tile_m + j * 64 + st_row;
            ar = ar < M ? ar : M - 1;  // clamp (stores are guarded)
            const _Float16* ag = A + (size_t)ar * K + kt + st_kc;
            __builtin_amdgcn_global_load_lds(
                (const __attribute__((address_space(1))) unsigned int*)ag,
                (__attribute__((address_space(3))) unsigned int*)
                    &As[buf][j * 2048 + (wid << 9)],
                16, 0, 0);
            const int br = tile_n + j * 64 + st_row;
            const _Float16* bg = Bt + (size_t)br * K + kt + st_kc;
            __builtin_amdgcn_global_load_lds(
                (const __attribute__((address_space(1))) unsigned int*)bg,
                (__attribute__((address_space(3))) unsigned int*)
                    &Bs[buf][j * 2048 + (wid << 9)],
                16, 0, 0);
        }
    };

    stage(0, 0);

    f32x4 acc[4][4] = {};
    const int fr = lane & 15;
    const int fk = (lane >> 4) << 3;
    const int niter = K >> 5;

    for (int it = 0; it < niter; ++it) {
        __syncthreads();  // drains vmcnt -> buf it&1 staged; prev reads done
        if (it + 1 < niter) stage((it + 1) & 1, (it + 1) << 5);
        const _Float16* as = As[it & 1];
        const _Float16* bs = Bs[it & 1];
        half8 af[4], bf[4];
#pragma unroll
        for (int mi = 0; mi < 4; ++mi)
            af[mi] = *(const half8*)&as[(wm + mi * 16 + fr) * 32 + fk];
#pragma unroll
        for (int ni = 0; ni < 4; ++ni)
            bf[ni] = *(const half8*)&bs[(wn + ni * 16 + fr) * 32 + fk];
#pragma unroll
        for (int mi = 0; mi < 4; ++mi)
#pragma unroll
            for (int ni = 0; ni < 4; ++ni)
                acc[mi][ni] = __builtin_amdgcn_mfma_f32_16x16x32_f16(
                    af[mi], bf[ni], acc[mi][ni], 0, 0, 0);
    }
    __syncthreads();  // all ds_reads done before LDS zones are reused

    // epilogue: C/D layout col=lane&15, row=(lane>>4)*4+reg; transpose via
    // wave-private 4KB LDS zone -> coalesced half8 stores
    _Float16* zone = &As[0][0] + wid * 2048;
    const int cl = lane & 15;
    const int rq = (lane >> 4) << 2;
    const int col0 = tile_n + wn;
    const int r0 = tile_m + wm;
#pragma unroll
    for (int mi = 0; mi < 4; ++mi) {
#pragma unroll
        for (int ni = 0; ni < 4; ++ni) {
            const float cb = catbias[col0 + ni * 16 + cl];
#pragma unroll
            for (int r = 0; r < 4; ++r)
                zone[(rq + r) * 72 + ni * 16 + cl] = f2h(acc[mi][ni][r] + cb);
        }
#pragma unroll
        for (int j = 0; j < 2; ++j) {
            const int rr = j * 8 + (lane >> 3);
            const int row = r0 + mi * 16 + rr;
            const half8 v = *(const half8*)&zone[rr * 72 + (lane & 7) * 8];
            if (row < M)
                *(half8*)&O[(size_t)row * N + col0 + (lane & 7) * 8] = v;
        }
    }
}

// ---------------------------------------------------------------------------
// Flat gather, one wave per node, fp16 [K(D)|QV(2D)|S(D)] rows (stride 4D,
// row NN = zeros for padded ELL slots). kpre/exp2 sigmoid; uniform rounds of
// 8 edges; ping-pong 2x8 load pipeline (16 edges in flight).
// MODE 0: write fp16 Hh[node][D]. MODE 1 (D=64): fused row-softmax -> out.
template <int D, int MODE>
__device__ __forceinline__ void gather_flat(
    int node, const int* __restrict__ deg,
    const unsigned short* __restrict__ col, const _Float16* __restrict__ KQVS,
    _Float16* __restrict__ Hh, float* __restrict__ out) {
    constexpr int DV = D / 64;
    constexpr int D4 = 4 * D;
    using qv_t = typename std::conditional<
        DV == 4, half8,
        typename std::conditional<DV == 2, half4, half2v>::type>::type;

    const int lane = threadIdx.x & 63;
    const int ld = lane * DV;
    const _Float16* nrow = KQVS + (size_t)node * D4;

    int dg = deg[node];
    dg = dg < ELLW ? dg : ELLW;
    const int R = (dg + 7) >> 3;  // wave-uniform rounds
    const int idx = (int)col[node * ELLW + lane];  // padded slots -> NN

    float kpre[DV], acc[DV];
    {
        if constexpr (DV == 4) {
            const half4 u = *(const half4*)(nrow + ld);
#pragma unroll
            for (int t = 0; t < 4; ++t) kpre[t] = (float)u[t] * NL2E;
        } else if constexpr (DV == 2) {
            const half2v u = *(const half2v*)(nrow + ld);
            kpre[0] = (float)u[0] * NL2E;
            kpre[1] = (float)u[1] * NL2E;
        } else {
            kpre[0] = (float)nrow[ld] * NL2E;
        }
    }
#pragma unroll
    for (int t = 0; t < DV; ++t) acc[t] = 0.f;

    const _Float16* qvbase = KQVS + D + 2 * ld;

    auto ld8 = [&](int r, qv_t* u) {
#pragma unroll
        for (int j = 0; j < 8; ++j) {
            const int s = __shfl(idx, r * 8 + j, 64);
            u[j] = *(const qv_t*)(qvbase + (size_t)s * D4);
        }
    };
    auto cp8 = [&](const qv_t* u) {
#pragma unroll
        for (int j = 0; j < 8; ++j)
#pragma unroll
            for (int t = 0; t < DV; ++t) {
                const float e = __builtin_amdgcn_exp2f(
                    fmaf((float)u[j][t], NL2E, kpre[t]));
                acc[t] = fmaf((float)u[j][DV + t],
                              __builtin_amdgcn_rcpf(1.f + e), acc[t]);
            }
    };

    qv_t ua[8], ub[8];
    if (R > 0) {
        ld8(0, ua);
        for (int i = 1; i < R; ++i) {  // load round i while computing i-1
            if (i & 1) { ld8(i, ub); cp8(ua); }
            else       { ld8(i, ua); cp8(ub); }
        }
        if (R & 1) cp8(ua); else cp8(ub);
    }

    // h = skip + agg
    float h[DV];
    {
        if constexpr (DV == 4) {
            const half4 u = *(const half4*)(nrow + 3 * D + ld);
#pragma unroll
            for (int t = 0; t < 4; ++t) h[t] = (float)u[t] + acc[t];
        } else if constexpr (DV == 2) {
            const half2v u = *(const half2v*)(nrow + 3 * D + ld);
            h[0] = (float)u[0] + acc[0];
            h[1] = (float)u[1] + acc[1];
        } else {
            h[0] = (float)nrow[3 * D + ld] + acc[0];
        }
    }

    if constexpr (MODE == 0) {
        _Float16* op = Hh + (size_t)node * D + ld;
        if constexpr (DV == 4) {
            half4 o;
#pragma unroll
            for (int t = 0; t < 4; ++t) o[t] = f2h(h[t]);
            *(half4*)op = o;
        } else if constexpr (DV == 2) {
            half2v o;
            o[0] = f2h(h[0]); o[1] = f2h(h[1]);
            *(half2v*)op = o;
        } else {
            op[0] = f2h(h[0]);
        }
    } else {
        static_assert(MODE == 0 || DV == 1, "softmax fusion needs D==64");
        float m = h[0];
#pragma unroll
        for (int off = 32; off > 0; off >>= 1)
            m = fmaxf(m, __shfl_xor(m, off, 64));
        const float ex = __expf(h[0] - m);
        float sm = ex;
#pragma unroll
        for (int off = 32; off > 0; off >>= 1) sm += __shfl_xor(sm, off, 64);
        out[(size_t)node * 64 + lane] = ex * __builtin_amdgcn_rcpf(sm);
    }
}

// ---------------------------------------------------------------------------
__global__ __launch_bounds__(256, 3) void mega_kernel(MegaParams P) {
    const unsigned NB = gridDim.x;
    const int tid = threadIdx.x;
    const int gtid = blockIdx.x * 256 + tid;
    const int gsz = NB * 256;

    // ============ P0: setup ============
    for (int i = gtid; i < NN; i += gsz) P.deg[i] = 0;
    {
        unsigned* e = (unsigned*)P.ell;  // pattern NN,NN per uint
        for (int i = gtid; i < NN * ELLW / 2; i += gsz) e[i] = 0x4E204E20u;
    }
    {
        unsigned* z = (unsigned*)(P.KQVS + (size_t)NN * 1024);  // L1 zero row
        for (int i = gtid; i < 512; i += gsz) z[i] = 0u;
    }
    if (blockIdx.x == 0) {
        // int64-vs-int32 edge_index probe (see R0 notes)
        __shared__ int nz;
        if (tid == 0) nz = 0;
        __syncthreads();
        int c = 0;
        for (int t = tid; t < 1024; t += 256)
            if (P.ei[2 * t + 1] != 0) c = 1;
        if (c) atomicAdd(&nz, 1);
        __syncthreads();
        if (tid == 0) *P.i64flag = (nz == 0) ? 1 : 0;
    }
    // weight prep: Wt[p][k] = W[grp][k][dim] per flat layout
    //   [0,D)=k, [D,3D)=qv interleaved in DV-groups, [3D,4D)=skip
    for (int idx = gtid; idx < 425984; idx += gsz) {
        int layer, li, K, D, s;
        if (idx < 262144)      { layer = 0; li = idx;          K = 256; D = 256; s = 2; }
        else if (idx < 393216) { layer = 1; li = idx - 262144; K = 256; D = 128; s = 1; }
        else                   { layer = 2; li = idx - 393216; K = 128; D = 64;  s = 0; }
        const int p = li / K;
        const int k = li - p * K;
        const int DV = D >> 6;
        int grp, c;
        if (p < D) {
            grp = 0; c = p;
        } else if (p < 3 * D) {
            const int t = p - D;
            const int g = t >> (s + 1);
            const int r = t & (2 * DV - 1);
            if (r < DV) { grp = 1; c = g * DV + r; }
            else        { grp = 2; c = g * DV + r - DV; }
        } else {
            grp = 3; c = p - 3 * D;
        }
        P.wt[layer][(size_t)p * K + k] =
            f2h(P.w[layer][grp][(size_t)k * D + c]);
        if (k == 0) P.cb[layer][p] = P.b[layer][grp][c];
    }
    // input cast fp32 -> fp16
    for (int i = gtid; i < 640000; i += gsz) {
        const int o = i * 8;
        const float4 f0 = *(const float4*)(P.x + o);
        const float4 f1 = *(const float4*)(P.x + o + 4);
        half8 h;
        h[0] = f2h(f0.x); h[1] = f2h(f0.y); h[2] = f2h(f0.z); h[3] = f2h(f0.w);
        h[4] = f2h(f1.x); h[5] = f2h(f1.y); h[6] = f2h(f1.z); h[7] = f2h(f1.w);
        *(half8*)(P.Xh + o) = h;
    }
    gbar(P.bar, 1u * NB);

    // ============ P1: GEMM1 (1256 tiles) || ELL fill (1250 chunks) ============
    for (int u = blockIdx.x; u < 2506; u += NB) {
        if (u < 1256) {
            gemm_tile(u % 157, u / 157, P.Xh, P.wt[0], P.cb[0], P.KQVS, NN,
                      256, 1024);
        } else {
            const int e = (u - 1256) * 256 + tid;
            if (e < EE) {
                int src, dst;
                if (*P.i64flag) {
                    const long long* p = (const long long*)P.ei;
                    src = (int)p[e];
                    dst = (int)p[EE + e];
                } else {
                    src = P.ei[e];
                    dst = P.ei[EE + e];
                }
                const int pos = atomicAdd(&P.deg[dst], 1);
                if (pos < ELLW) P.ell[dst * ELLW + pos] = (unsigned short)src;
            }
        }
    }
    gbar(P.bar, 2u * NB);

    // ============ P2: gather layer 1 ============
    for (int u = blockIdx.x; u < 5000; u += NB) {
        const int node = u * 4 + (tid >> 6);
        gather_flat<256, 0>(node, P.deg, P.ell, P.KQVS, P.H1h, nullptr);
    }
    gbar(P.bar, 3u * NB);

    // ============ P3: GEMM2 (628 tiles) + zero L2 row ============
    for (int u = blockIdx.x; u < 629; u += NB) {
        if (u < 628) {
            gemm_tile(u % 157, u / 157, P.H1h, P.wt[1], P.cb[1], P.KQVS, NN,
                      256, 512);
        } else {
            unsigned* z = (unsigned*)(P.KQVS + (size_t)NN * 512);
            if (tid < 256) z[tid] = 0u;
        }
    }
    gbar(P.bar, 4u * NB);

    // ============ P4: gather layer 2 ============
    for (int u = blockIdx.x; u < 5000; u += NB) {
        const int node = u * 4 + (tid >> 6);
        gather_flat<128, 0>(node, P.deg, P.ell, P.KQVS, P.H2h, nullptr);
    }
    gbar(P.bar, 5u * NB);

    // ============ P5: GEMM3 (314 tiles) + zero L3 row ============
    for (int u = blockIdx.x; u < 315; u += NB) {
        if (u < 314) {
            gemm_tile(u % 157, u / 157, P.H2h, P.wt[2], P.cb[2], P.KQVS, NN,
                      128, 256);
        } else {
            unsigned* z = (unsigned*)(P.KQVS + (size_t)NN * 256);
            if (tid < 128) z[tid] = 0u;
        }
    }
    gbar(P.bar, 6u * NB);

    // ============ P6: gather layer 3 + softmax ============
    for (int u = blockIdx.x; u < 5000; u += NB) {
        const int node = u * 4 + (tid >> 6);
        gather_flat<64, 1>(node, P.deg, P.ell, P.KQVS, nullptr, P.out);
    }
}

// ---------------------------------------------------------------------------
extern "C" void kernel_launch(void* const* d_in, const int* in_sizes, int n_in,
                              void* d_out, int out_size, void* d_ws,
                              size_t ws_size, hipStream_t stream) {
    unsigned* bar = (unsigned*)d_ws;  // 64 B, memset to 0 below
    char* w = (char*)d_ws + 64;

    MegaParams P;
    P.x = (const float*)d_in[0];
    P.ei = (const int*)d_in[1];
    P.w[0][0] = (const float*)d_in[2];  P.b[0][0] = (const float*)d_in[3];
    P.w[0][1] = (const float*)d_in[4];  P.b[0][1] = (const float*)d_in[5];
    P.w[0][2] = (const float*)d_in[6];  P.b[0][2] = (const float*)d_in[7];
    P.w[1][0] = (const float*)d_in[8];  P.b[1][0] = (const float*)d_in[9];
    P.w[1][1] = (const float*)d_in[10]; P.b[1][1] = (const float*)d_in[11];
    P.w[1][2] = (const float*)d_in[12]; P.b[1][2] = (const float*)d_in[13];
    P.w[2][0] = (const float*)d_in[14]; P.b[2][0] = (const float*)d_in[15];
    P.w[2][1] = (const float*)d_in[16]; P.b[2][1] = (const float*)d_in[17];
    P.w[2][2] = (const float*)d_in[18]; P.b[2][2] = (const float*)d_in[19];
    P.w[0][3] = (const float*)d_in[20]; P.b[0][3] = (const float*)d_in[21];
    P.w[1][3] = (const float*)d_in[22]; P.b[1][3] = (const float*)d_in[23];
    P.w[2][3] = (const float*)d_in[24]; P.b[2][3] = (const float*)d_in[25];

    P.Xh = (_Float16*)w;     w += (size_t)NN * 256 * 2;
    P.KQVS = (_Float16*)w;   w += (size_t)(NN + 1) * 1024 * 2;
    P.H1h = (_Float16*)w;    w += (size_t)NN * 256 * 2;
    P.H2h = (_Float16*)w;    w += (size_t)NN * 128 * 2;
    P.wt[0] = (_Float16*)w;  w += (size_t)1024 * 256 * 2;
    P.wt[1] = (_Float16*)w;  w += (size_t)512 * 256 * 2;
    P.wt[2] = (_Float16*)w;  w += (size_t)256 * 128 * 2;
    P.cb[0] = (float*)w;     w += 1024 * 4;
    P.cb[1] = (float*)w;     w += 512 * 4;
    P.cb[2] = (float*)w;     w += 256 * 4;
    P.i64flag = (int*)w;     w += 16;
    P.deg = (int*)w;         w += (size_t)NN * 4;
    P.ell = (unsigned short*)w;  w += (size_t)NN * ELLW * 2;
    P.bar = bar;
    P.out = (float*)d_out;

    // grid = co-resident capacity (runtime's own occupancy math) so the
    // in-kernel grid barrier is deadlock-free.
    int nb = 0;
    hipOccupancyMaxActiveBlocksPerMultiprocessor(&nb, mega_kernel, 256, 0);
    if (nb < 1) nb = 1;
    int grid = nb * 256;  // 256 CUs on MI355X
    if (grid > 1280) grid = 1280;

    hipMemsetAsync(bar, 0, 64, stream);
    mega_kernel<<<grid, 256, 0, stream>>>(P);
}

// Round 12
// 264.463 us; speedup vs baseline: 2.2953x; 2.2953x over previous
//
#include <hip/hip_runtime.h>
#include <hip/hip_bf16.h>
#include <type_traits>

// ResGatedGraphConv x3 + softmax.
// R12: revert R11 mega-kernel (grid-barrier spin disaster: VALUBusy 5%).
// Back to R8's 7-launch structure (best: 262us) + validated gather upgrades:
// zero-row padded ELL -> uniform rounds (no per-lane predication), kpre/exp2
// sigmoid, ping-pong 2x8 edge-load pipeline (16 loads in flight).
// fp16 MFMA GEMMs, flat fp16 [K|QV|S] rows, fp32 accumulate.
// N=20000 nodes, E=320000 edges, dims 256 -> 256 -> 128 -> 64.

#define NN 20000
#define EE 320000
#define ELLW 64   // max degree slot; Poisson(16) => P(deg>64) ~ 1e-19
#define NL2E -1.4426950408889634f  // -log2(e)

typedef _Float16 half8 __attribute__((ext_vector_type(8)));
typedef _Float16 half4 __attribute__((ext_vector_type(4)));
typedef _Float16 half2v __attribute__((ext_vector_type(2)));
typedef float f32x4 __attribute__((ext_vector_type(4)));

__device__ __forceinline__ _Float16 f2h(float f) { return (_Float16)f; }

// ---------------------------------------------------------------------------
// Weight layout (baked into Wt so the GEMM writes final memory order), per
// node row of width 4D: [0,D)=key, [D,3D)=q/v interleaved in DV-groups
// (DV=D/64; group g holds q[g*DV..+DV) then v[g*DV..+DV)), [3D,4D)=skip
// (conv output bias folded into catbias). Row NN of the output = zeros
// (padded ELL slots point there -> exact no-op contributions).
struct PrepArgs {
    const float* w[3][4];  // [layer][grp k,q,v,skip]
    const float* b[3][4];  // [layer][grp] (skip slot = conv bias)
    _Float16* wt[3];
    float* cb[3];
};

// K0 block ranges:
//   [0,79)        zero deg
//   79            i64 probe
//   [80,1744)     weight prep (425984 elems)
//   [1744,4244)   fp32->fp16 cast of x (5.12M elems, 8/thread)
//   [4244,6744)   ELL pattern-init to NN (0x4E204E20)
//   6744          zero row NN of layer-1 KQVS (1024 halfs)
__global__ __launch_bounds__(256) void setup_all_kernel(
    const int* __restrict__ ei, int* __restrict__ deg, int* __restrict__ flag,
    const float* __restrict__ x, _Float16* __restrict__ Xh,
    unsigned int* __restrict__ ell_i, unsigned int* __restrict__ kqvs_i,
    PrepArgs a) {
    const int b = blockIdx.x;
    const int tid = threadIdx.x;
    if (b < 79) {
        const int i = b * 256 + tid;
        if (i < NN) deg[i] = 0;
    } else if (b == 79) {
        // int64-vs-int32 edge_index probe: if data is int64 (values < 2^31),
        // every odd int32 word is 0 (see R0 notes).
        __shared__ int nz;
        if (tid == 0) nz = 0;
        __syncthreads();
        int c = 0;
        for (int t = tid; t < 1024; t += 256)
            if (ei[2 * t + 1] != 0) c = 1;
        if (c) atomicAdd(&nz, 1);
        __syncthreads();
        if (tid == 0) *flag = (nz == 0) ? 1 : 0;
    } else if (b < 1744) {
        const int idx = (b - 80) * 256 + tid;  // < 425984
        int layer, li, K, D, s;
        if (idx < 262144)      { layer = 0; li = idx;          K = 256; D = 256; s = 2; }
        else if (idx < 393216) { layer = 1; li = idx - 262144; K = 256; D = 128; s = 1; }
        else                   { layer = 2; li = idx - 393216; K = 128; D = 64;  s = 0; }
        const int p = li / K;
        const int k = li - p * K;
        const int DV = D >> 6;
        int grp, c;
        if (p < D) {
            grp = 0; c = p;
        } else if (p < 3 * D) {
            const int t = p - D;
            const int g = t >> (s + 1);
            const int r = t & (2 * DV - 1);
            if (r < DV) { grp = 1; c = g * DV + r; }
            else        { grp = 2; c = g * DV + r - DV; }
        } else {
            grp = 3; c = p - 3 * D;
        }
        a.wt[layer][(size_t)p * K + k] =
            f2h(a.w[layer][grp][(size_t)k * D + c]);
        if (k == 0) a.cb[layer][p] = a.b[layer][grp][c];
    } else if (b < 4244) {
        const int i = ((b - 1744) * 256 + tid) * 8;
        if (i < NN * 256) {
            const float4 f0 = *(const float4*)(x + i);
            const float4 f1 = *(const float4*)(x + i + 4);
            half8 h;
            h[0] = f2h(f0.x); h[1] = f2h(f0.y); h[2] = f2h(f0.z); h[3] = f2h(f0.w);
            h[4] = f2h(f1.x); h[5] = f2h(f1.y); h[6] = f2h(f1.z); h[7] = f2h(f1.w);
            *(half8*)(Xh + i) = h;
        }
    } else if (b < 6744) {
        const int i = (b - 4244) * 256 + tid;  // ELL as uints: 640000
        if (i < NN * ELLW / 2) ell_i[i] = 0x4E204E20u;  // two ushort NN
    } else {
        // zero row NN of layer-1 output (1024 halfs = 512 uints)
        for (int i = tid; i < 512; i += 256)
            kqvs_i[(size_t)NN * 512 + i] = 0u;
    }
}

// ---------------------------------------------------------------------------
// fp16 MFMA GEMM tile: C = A[M,K] @ Bt[N,K]^T + catbias -> fp16 O[M][N].
// 128x128 tile, BK=32, double-buffered staging, one barrier per K-iter.
// Epilogue transposes each wave's 64x64 tile through a private 4KB LDS zone
// for coalesced half8 stores. Bt columns pre-permuted (see PrepArgs).
__device__ __forceinline__ void gemm_tile(
    int bm, int bn, const _Float16* __restrict__ A,
    const _Float16* __restrict__ Bt, const float* __restrict__ catbias,
    _Float16* __restrict__ O, int M, int K, int N) {
    __shared__ _Float16 As[2][4096];  // [buf][row*32+k], 16 KB
    __shared__ _Float16 Bs[2][4096];

    const int tid = threadIdx.x;
    const int wid = tid >> 6;
    const int lane = tid & 63;
    const int tile_m = bm * 128;
    const int tile_n = bn * 128;
    const int wm = (wid & 1) * 64;
    const int wn = (wid >> 1) * 64;

    const int st_row = (wid << 4) + (lane >> 2);
    const int st_kc = (lane & 3) << 3;

    auto stage = [&](int buf, int kt) {
#pragma unroll
        for (int j = 0; j < 2; ++j) {
            int ar = tile_m + j * 64 + st_row;
            ar = ar < M ? ar : M - 1;  // clamp (stores are guarded)
            const _Float16* ag = A + (size_t)ar * K + kt + st_kc;
            __builtin_amdgcn_global_load_lds(
                (const __attribute__((address_space(1))) unsigned int*)ag,
                (__attribute__((address_space(3))) unsigned int*)
                    &As[buf][j * 2048 + (wid << 9)],
                16, 0, 0);
            const int br = tile_n + j * 64 + st_row;
            const _Float16* bg = Bt + (size_t)br * K + kt + st_kc;
            __builtin_amdgcn_global_load_lds(
                (const __attribute__((address_space(1))) unsigned int*)bg,
                (__attribute__((address_space(3))) unsigned int*)
                    &Bs[buf][j * 2048 + (wid << 9)],
                16, 0, 0);
        }
    };

    stage(0, 0);

    f32x4 acc[4][4] = {};
    const int fr = lane & 15;
    const int fk = (lane >> 4) << 3;
    const int niter = K >> 5;

    for (int it = 0; it < niter; ++it) {
        __syncthreads();  // drains vmcnt -> buf it&1 staged; prev reads done
        if (it + 1 < niter) stage((it + 1) & 1, (it + 1) << 5);
        const _Float16* as = As[it & 1];
        const _Float16* bs = Bs[it & 1];
        half8 af[4], bf[4];
#pragma unroll
        for (int mi = 0; mi < 4; ++mi)
            af[mi] = *(const half8*)&as[(wm + mi * 16 + fr) * 32 + fk];
#pragma unroll
        for (int ni = 0; ni < 4; ++ni)
            bf[ni] = *(const half8*)&bs[(wn + ni * 16 + fr) * 32 + fk];
#pragma unroll
        for (int mi = 0; mi < 4; ++mi)
#pragma unroll
            for (int ni = 0; ni < 4; ++ni)
                acc[mi][ni] = __builtin_amdgcn_mfma_f32_16x16x32_f16(
                    af[mi], bf[ni], acc[mi][ni], 0, 0, 0);
    }
    __syncthreads();  // all ds_reads done before LDS zones are reused

    // epilogue: C/D layout col=lane&15, row=(lane>>4)*4+reg
    _Float16* zone = &As[0][0] + wid * 2048;  // private 4 KB
    const int cl = lane & 15;
    const int rq = (lane >> 4) << 2;
    const int col0 = tile_n + wn;
    const int r0 = tile_m + wm;
#pragma unroll
    for (int mi = 0; mi < 4; ++mi) {
#pragma unroll
        for (int ni = 0; ni < 4; ++ni) {
            const float cb = catbias[col0 + ni * 16 + cl];
#pragma unroll
            for (int r = 0; r < 4; ++r)
                zone[(rq + r) * 72 + ni * 16 + cl] = f2h(acc[mi][ni][r] + cb);
        }
#pragma unroll
        for (int j = 0; j < 2; ++j) {
            const int rr = j * 8 + (lane >> 3);
            const int row = r0 + mi * 16 + rr;
            const half8 v = *(const half8*)&zone[rr * 72 + (lane & 7) * 8];
            if (row < M)
                *(half8*)&O[(size_t)row * N + col0 + (lane & 7) * 8] = v;
        }
    }
}

// Standalone GEMM (layers 2/3). Last block zeroes row NN of O (padded-edge
// target for the following gather).
__global__ __launch_bounds__(256) void gemm_kernel(
    const _Float16* __restrict__ A, const _Float16* __restrict__ Bt,
    const float* __restrict__ catbias, _Float16* __restrict__ O, int M, int K,
    int N, int mblocks, int ntiles) {
    if ((int)blockIdx.x >= ntiles) {
        unsigned* z = (unsigned*)(O + (size_t)NN * N);
        for (int i = threadIdx.x; i < N / 2; i += 256) z[i] = 0u;
        return;
    }
    gemm_tile(blockIdx.x % mblocks, blockIdx.x / mblocks, A, Bt, catbias, O, M,
              K, N);
}

// K1: blocks [0,1256) = GEMM layer 1; [1256,2506) = ELL fill (independent).
__global__ __launch_bounds__(256) void gemm1_fill_kernel(
    const _Float16* __restrict__ A, const _Float16* __restrict__ Bt,
    const float* __restrict__ catbias, _Float16* __restrict__ O,
    const int* __restrict__ ei, const int* __restrict__ i64flag,
    int* __restrict__ deg, unsigned short* __restrict__ col) {
    if (blockIdx.x < 1256) {
        gemm_tile(blockIdx.x % 157, blockIdx.x / 157, A, Bt, catbias, O, NN,
                  256, 1024);
        return;
    }
    const int e = (blockIdx.x - 1256) * 256 + threadIdx.x;
    if (e >= EE) return;
    int src, dst;
    if (*i64flag) {
        const long long* p = (const long long*)ei;
        src = (int)p[e];
        dst = (int)p[EE + e];
    } else {
        src = ei[e];
        dst = ei[EE + e];
    }
    const int pos = atomicAdd(&deg[dst], 1);
    if (pos < ELLW) col[dst * ELLW + pos] = (unsigned short)src;
}

// ---------------------------------------------------------------------------
// Flat gather, one wave per node, fp16 [K(D)|QV(2D)|S(D)] rows (stride 4D,
// row NN = zeros for padded ELL slots). kpre/exp2 sigmoid; uniform rounds of
// 8 edges; ping-pong 2x8 load pipeline (16 edges in flight).
// MODE 0: write fp16 Hh[node][D]. MODE 1 (D=64): fused row-softmax -> out.
template <int D, int MODE>
__global__ __launch_bounds__(256) void gather_kernel(
    const int* __restrict__ deg, const unsigned short* __restrict__ col,
    const _Float16* __restrict__ KQVS, _Float16* __restrict__ Hh,
    float* __restrict__ out) {
    constexpr int DV = D / 64;
    constexpr int D4 = 4 * D;
    using qv_t = typename std::conditional<
        DV == 4, half8,
        typename std::conditional<DV == 2, half4, half2v>::type>::type;

    const int node = blockIdx.x * 4 + (threadIdx.x >> 6);  // grid covers NN
    const int lane = threadIdx.x & 63;
    const int ld = lane * DV;
    const _Float16* nrow = KQVS + (size_t)node * D4;

    int dg = deg[node];
    dg = dg < ELLW ? dg : ELLW;
    const int R = (dg + 7) >> 3;  // wave-uniform rounds
    const int idx = (int)col[node * ELLW + lane];  // padded slots -> NN

    float kpre[DV], acc[DV];
    {
        if constexpr (DV == 4) {
            const half4 u = *(const half4*)(nrow + ld);
#pragma unroll
            for (int t = 0; t < 4; ++t) kpre[t] = (float)u[t] * NL2E;
        } else if constexpr (DV == 2) {
            const half2v u = *(const half2v*)(nrow + ld);
            kpre[0] = (float)u[0] * NL2E;
            kpre[1] = (float)u[1] * NL2E;
        } else {
            kpre[0] = (float)nrow[ld] * NL2E;
        }
    }
#pragma unroll
    for (int t = 0; t < DV; ++t) acc[t] = 0.f;

    const _Float16* qvbase = KQVS + D + 2 * ld;

    auto ld8 = [&](int r, qv_t* u) {
#pragma unroll
        for (int j = 0; j < 8; ++j) {
            const int s = __shfl(idx, r * 8 + j, 64);
            u[j] = *(const qv_t*)(qvbase + (size_t)s * D4);
        }
    };
    auto cp8 = [&](const qv_t* u) {
#pragma unroll
        for (int j = 0; j < 8; ++j)
#pragma unroll
            for (int t = 0; t < DV; ++t) {
                const float e = __builtin_amdgcn_exp2f(
                    fmaf((float)u[j][t], NL2E, kpre[t]));
                acc[t] = fmaf((float)u[j][DV + t],
                              __builtin_amdgcn_rcpf(1.f + e), acc[t]);
            }
    };

    qv_t ua[8], ub[8];
    if (R > 0) {
        ld8(0, ua);
        for (int i = 1; i < R; ++i) {  // load round i while computing i-1
            if (i & 1) { ld8(i, ub); cp8(ua); }
            else       { ld8(i, ua); cp8(ub); }
        }
        if (R & 1) cp8(ua); else cp8(ub);
    }

    // h = skip + agg
    float h[DV];
    {
        if constexpr (DV == 4) {
            const half4 u = *(const half4*)(nrow + 3 * D + ld);
#pragma unroll
            for (int t = 0; t < 4; ++t) h[t] = (float)u[t] + acc[t];
        } else if constexpr (DV == 2) {
            const half2v u = *(const half2v*)(nrow + 3 * D + ld);
            h[0] = (float)u[0] + acc[0];
            h[1] = (float)u[1] + acc[1];
        } else {
            h[0] = (float)nrow[3 * D + ld] + acc[0];
        }
    }

    if constexpr (MODE == 0) {
        _Float16* op = Hh + (size_t)node * D + ld;
        if constexpr (DV == 4) {
            half4 o;
#pragma unroll
            for (int t = 0; t < 4; ++t) o[t] = f2h(h[t]);
            *(half4*)op = o;
        } else if constexpr (DV == 2) {
            half2v o;
            o[0] = f2h(h[0]); o[1] = f2h(h[1]);
            *(half2v*)op = o;
        } else {
            op[0] = f2h(h[0]);
        }
    } else {
        static_assert(MODE == 0 || DV == 1, "softmax fusion needs D==64");
        float m = h[0];
#pragma unroll
        for (int off = 32; off > 0; off >>= 1)
            m = fmaxf(m, __shfl_xor(m, off, 64));
        const float ex = __expf(h[0] - m);
        float sm = ex;
#pragma unroll
        for (int off = 32; off > 0; off >>= 1) sm += __shfl_xor(sm, off, 64);
        out[(size_t)node * 64 + lane] = ex * __builtin_amdgcn_rcpf(sm);
    }
}

// ---------------------------------------------------------------------------
extern "C" void kernel_launch(void* const* d_in, const int* in_sizes, int n_in,
                              void* d_out, int out_size, void* d_ws,
                              size_t ws_size, hipStream_t stream) {
    const float* x = (const float*)d_in[0];
    const int* ei = (const int*)d_in[1];

    char* w = (char*)d_ws;
    _Float16* Xh = (_Float16*)w;     w += (size_t)NN * 256 * 2;
    _Float16* KQVS = (_Float16*)w;   w += (size_t)(NN + 1) * 1024 * 2;
    _Float16* H1h = (_Float16*)w;    w += (size_t)NN * 256 * 2;
    _Float16* H2h = (_Float16*)w;    w += (size_t)NN * 128 * 2;
    _Float16* Wt1 = (_Float16*)w;    w += (size_t)1024 * 256 * 2;
    _Float16* Wt2 = (_Float16*)w;    w += (size_t)512 * 256 * 2;
    _Float16* Wt3 = (_Float16*)w;    w += (size_t)256 * 128 * 2;
    float* cb1 = (float*)w;          w += 1024 * 4;
    float* cb2 = (float*)w;          w += 512 * 4;
    float* cb3 = (float*)w;          w += 256 * 4;
    int* i64flag = (int*)w;          w += 16;
    int* deg = (int*)w;              w += (size_t)NN * 4;
    unsigned short* ell = (unsigned short*)w;  w += (size_t)NN * ELLW * 2;

    const dim3 blk(256);
    const int gblocks = NN / 4;  // 5000, exact

    PrepArgs pa;
    pa.w[0][0] = (const float*)d_in[2];  pa.b[0][0] = (const float*)d_in[3];
    pa.w[0][1] = (const float*)d_in[4];  pa.b[0][1] = (const float*)d_in[5];
    pa.w[0][2] = (const float*)d_in[6];  pa.b[0][2] = (const float*)d_in[7];
    pa.w[1][0] = (const float*)d_in[8];  pa.b[1][0] = (const float*)d_in[9];
    pa.w[1][1] = (const float*)d_in[10]; pa.b[1][1] = (const float*)d_in[11];
    pa.w[1][2] = (const float*)d_in[12]; pa.b[1][2] = (const float*)d_in[13];
    pa.w[2][0] = (const float*)d_in[14]; pa.b[2][0] = (const float*)d_in[15];
    pa.w[2][1] = (const float*)d_in[16]; pa.b[2][1] = (const float*)d_in[17];
    pa.w[2][2] = (const float*)d_in[18]; pa.b[2][2] = (const float*)d_in[19];
    pa.w[0][3] = (const float*)d_in[20]; pa.b[0][3] = (const float*)d_in[21];
    pa.w[1][3] = (const float*)d_in[22]; pa.b[1][3] = (const float*)d_in[23];
    pa.w[2][3] = (const float*)d_in[24]; pa.b[2][3] = (const float*)d_in[25];
    pa.wt[0] = Wt1; pa.wt[1] = Wt2; pa.wt[2] = Wt3;
    pa.cb[0] = cb1; pa.cb[1] = cb2; pa.cb[2] = cb3;

    // K0: zero deg | probe | prep | cast | ELL init | zero row  (6745 blocks)
    setup_all_kernel<<<6745, blk, 0, stream>>>(
        ei, deg, i64flag, x, Xh, (unsigned int*)ell, (unsigned int*)KQVS, pa);

    // K1: GEMM layer-1 (1256 blocks) || ELL fill (1250 blocks)
    gemm1_fill_kernel<<<2506, blk, 0, stream>>>(Xh, Wt1, cb1, KQVS, ei,
                                                i64flag, deg, ell);
    gather_kernel<256, 0><<<gblocks, blk, 0, stream>>>(deg, ell, KQVS, H1h,
                                                       nullptr);

    // ---- layer 2: 256 -> 128 ----
    gemm_kernel<<<157 * 4 + 1, blk, 0, stream>>>(H1h, Wt2, cb2, KQVS, NN, 256,
                                                 512, 157, 628);
    gather_kernel<128, 0><<<gblocks, blk, 0, stream>>>(deg, ell, KQVS, H2h,
                                                       nullptr);

    // ---- layer 3: 128 -> 64, softmax fused into gather ----
    gemm_kernel<<<157 * 2 + 1, blk, 0, stream>>>(H2h, Wt3, cb3, KQVS, NN, 128,
                                                 256, 157, 314);
    gather_kernel<64, 1><<<gblocks, blk, 0, stream>>>(deg, ell, KQVS, nullptr,
                                                      (float*)d_out);
}